// Round 2
// baseline (637.645 us; speedup 1.0000x reference)
//
#include <hip/hip_runtime.h>
#include <hip/hip_bf16.h>

typedef __bf16 bf16x8 __attribute__((ext_vector_type(8)));
typedef float f32x4 __attribute__((ext_vector_type(4)));

// LDS byte offsets
#define LDS_HO 0        // 64 rows x 512B (h_other bf16 64x256); reused for h_new tile (64x128 bf16, stride 256)
#define LDS_X  32768    // 64 rows x 256B (x = [enc_in | enc_hid] bf16 64x128)
#define LDS_H  49152    // 64 rows x 256B (h bf16 64x128)

// workspace element offsets (ushort/bf16)
#define WS_WIH 0
#define WS_WHH 49152
#define WS_HENC 98304
#define WS_DEC 114688
#define WS_TOTAL 116736

__device__ __forceinline__ unsigned short f2bf(float f) {
    unsigned u = __float_as_uint(f);
    unsigned r = (u + 0x7FFFu + ((u >> 16) & 1u)) >> 16;   // RNE
    return (unsigned short)r;
}

// packed f32 pair -> 2x bf16 in one u32 (hardware RNE)
__device__ __forceinline__ unsigned cvt_pk_bf16(float a, float b) {
    unsigned r;
    asm("v_cvt_pk_bf16_f32 %0, %1, %2" : "=v"(r) : "v"(a), "v"(b));
    return r;
}

__device__ __forceinline__ float fast_rcp(float x) { return __builtin_amdgcn_rcpf(x); }
__device__ __forceinline__ float sigmf(float x) { return fast_rcp(1.0f + __expf(-x)); }
__device__ __forceinline__ float tanh_fast(float x) {
    float t = __expf(-2.0f * fabsf(x));
    float r = (1.0f - t) * fast_rcp(1.0f + t);
    return copysignf(r, x);
}

__global__ void convert_weights_kernel(const float* __restrict__ wih,
                                       const float* __restrict__ whh,
                                       const float* __restrict__ henc,
                                       const float* __restrict__ dec,
                                       unsigned short* __restrict__ ws) {
    int i = blockIdx.x * 256 + threadIdx.x;
    if (i >= WS_TOTAL) return;
    float v;
    if (i < WS_WHH)        v = wih[i];
    else if (i < WS_HENC)  v = whh[i - WS_WHH];
    else if (i < WS_DEC)   v = henc[i - WS_HENC];
    else { int d = i - WS_DEC; v = (d < 640) ? dec[d] : 0.0f; }   // dec padded to 16x128
    ws[i] = f2bf(v);
}

__launch_bounds__(512, 4)
__global__ void fused_rnn_kernel(const float* __restrict__ pos,
                                 const float* __restrict__ h_other,
                                 const float* __restrict__ h,
                                 const float* __restrict__ enc_W,
                                 const float* __restrict__ enc_b,
                                 const float* __restrict__ henc_b,
                                 const float* __restrict__ b_ih,
                                 const float* __restrict__ b_hh,
                                 const float* __restrict__ dec_b,
                                 const unsigned short* __restrict__ ws,
                                 float* __restrict__ out,
                                 float* __restrict__ hnew,
                                 int N) {
    __shared__ char sm[65536];
    const int tid = threadIdx.x;
    const int w   = tid >> 6;      // wave 0..7
    const int wm  = w >> 2;        // row half 0..1
    const int wc  = w & 3;         // col quarter 0..3
    const int l   = tid & 63;
    const int lg  = l >> 4;        // lane group 0..3
    const int ln  = l & 15;
    const int row0 = blockIdx.x * 64;

    // ---------------- Phase 0: stage tiles ----------------
    // h_other -> LDS_HO (bf16, 64x256, stride 512B, xor-swizzled)
    #pragma unroll
    for (int j = 0; j < 8; ++j) {
        int e0  = (tid + 512 * j) * 4;
        int row = e0 >> 8;
        int col = e0 & 255;
        int grow = row0 + row; if (grow > N - 1) grow = N - 1;
        float4 v = *reinterpret_cast<const float4*>(h_other + (size_t)grow * 256 + col);
        uint2 p;
        p.x = cvt_pk_bf16(v.x, v.y);
        p.y = cvt_pk_bf16(v.z, v.w);
        int boff = LDS_HO + row * 512 + ((col * 2) ^ ((row & 7) << 4));
        *reinterpret_cast<uint2*>(sm + boff) = p;
    }
    // h -> LDS_H (bf16, 64x128, stride 256B)
    #pragma unroll
    for (int j = 0; j < 4; ++j) {
        int e0  = (tid + 512 * j) * 4;
        int row = e0 >> 7;
        int col = e0 & 127;
        int grow = row0 + row; if (grow > N - 1) grow = N - 1;
        float4 v = *reinterpret_cast<const float4*>(h + (size_t)grow * 128 + col);
        uint2 p;
        p.x = cvt_pk_bf16(v.x, v.y);
        p.y = cvt_pk_bf16(v.z, v.w);
        int boff = LDS_H + row * 256 + ((col * 2) ^ ((row & 7) << 4));
        *reinterpret_cast<uint2*>(sm + boff) = p;
    }
    // E1 = relu(pos @ enc_W.T + enc_b) -> LDS_X cols 0..63
    {
        int row = tid >> 3;
        int c0  = (tid & 7) * 8;
        int grow = row0 + row; if (grow > N - 1) grow = N - 1;
        float p0 = pos[(size_t)grow * 2 + 0];
        float p1 = pos[(size_t)grow * 2 + 1];
        #pragma unroll
        for (int q = 0; q < 4; ++q) {
            int c = c0 + q * 2;
            float v0 = fmaxf(p0 * enc_W[c * 2]     + p1 * enc_W[c * 2 + 1]  + enc_b[c], 0.f);
            float v1 = fmaxf(p0 * enc_W[c * 2 + 2] + p1 * enc_W[c * 2 + 3]  + enc_b[c + 1], 0.f);
            unsigned pk = cvt_pk_bf16(v0, v1);
            int boff = LDS_X + row * 256 + ((c * 2) ^ ((row & 7) << 4));
            *reinterpret_cast<unsigned*>(sm + boff) = pk;
        }
    }
    __syncthreads();

    // ---------------- Phase 1: E2 = relu(h_other @ henc_W.T + henc_b) ----------------
    // wave (wm,wc): rows [32wm,32wm+32), E2 cols [16wc,16wc+16)
    {
        f32x4 acc[2];
        #pragma unroll
        for (int mt = 0; mt < 2; ++mt) acc[mt] = (f32x4){0.f, 0.f, 0.f, 0.f};
        #pragma unroll
        for (int ks = 0; ks < 8; ++ks) {
            bf16x8 af[2];
            #pragma unroll
            for (int mt = 0; mt < 2; ++mt) {
                int row = 32 * wm + mt * 16 + ln;
                int boff = LDS_HO + row * 512 + ((ks * 64 + lg * 16) ^ ((row & 7) << 4));
                af[mt] = *reinterpret_cast<const bf16x8*>(sm + boff);
            }
            const unsigned short* bp = ws + WS_HENC + (size_t)(16 * wc + ln) * 256 + ks * 32 + lg * 8;
            bf16x8 bf = *reinterpret_cast<const bf16x8*>(bp);
            #pragma unroll
            for (int mt = 0; mt < 2; ++mt)
                acc[mt] = __builtin_amdgcn_mfma_f32_16x16x32_bf16(af[mt], bf, acc[mt], 0, 0, 0);
        }
        int col = 16 * wc + ln;
        float bias = henc_b[col];
        #pragma unroll
        for (int mt = 0; mt < 2; ++mt) {
            #pragma unroll
            for (int i = 0; i < 4; ++i) {
                int row = 32 * wm + mt * 16 + lg * 4 + i;
                float v = fmaxf(acc[mt][i] + bias, 0.f);
                int boff = LDS_X + row * 256 + (((64 + col) * 2) ^ ((row & 7) << 4));
                *reinterpret_cast<unsigned short*>(sm + boff) = f2bf(v);
            }
        }
    }
    __syncthreads();

    // ---------------- Phase 2: gates ----------------
    // wave (wm,wc): rows [32wm,32wm+32), gate columns [32wc, 32wc+32)
    // jobs 0,1: r (K=256 over [x|h], W=[W_ih|W_hh]); 2,3: z; 4,5: xn (x only); 6,7: hn (h only)
    {
        f32x4 acc[2][8];
        #pragma unroll
        for (int a = 0; a < 2; ++a)
            #pragma unroll
            for (int b = 0; b < 8; ++b) acc[a][b] = (f32x4){0.f, 0.f, 0.f, 0.f};

        const unsigned short* WIH = ws + WS_WIH;
        const unsigned short* WHH = ws + WS_WHH;

        #pragma unroll
        for (int ks = 0; ks < 8; ++ks) {
            const int xbase = (ks < 4) ? LDS_X : LDS_H;
            const int kb = (ks & 3) * 64 + lg * 16;
            bf16x8 af[2];
            #pragma unroll
            for (int mt = 0; mt < 2; ++mt) {
                int row = 32 * wm + mt * 16 + ln;
                af[mt] = *reinterpret_cast<const bf16x8*>(sm + xbase + row * 256 + (kb ^ ((row & 7) << 4)));
            }
            const int kk = (ks & 3) * 32 + lg * 8;

            #define MFMA_JOB(job, Wptr, ob) { \
                bf16x8 bfr = *reinterpret_cast<const bf16x8*>((Wptr) + (size_t)((ob) + ln) * 128 + kk); \
                acc[0][job] = __builtin_amdgcn_mfma_f32_16x16x32_bf16(af[0], bfr, acc[0][job], 0, 0, 0); \
                acc[1][job] = __builtin_amdgcn_mfma_f32_16x16x32_bf16(af[1], bfr, acc[1][job], 0, 0, 0); }

            if (ks < 4) {
                MFMA_JOB(0, WIH, 32 * wc);
                MFMA_JOB(1, WIH, 32 * wc + 16);
                MFMA_JOB(2, WIH, 128 + 32 * wc);
                MFMA_JOB(3, WIH, 144 + 32 * wc);
                MFMA_JOB(4, WIH, 256 + 32 * wc);
                MFMA_JOB(5, WIH, 272 + 32 * wc);
            } else {
                MFMA_JOB(0, WHH, 32 * wc);
                MFMA_JOB(1, WHH, 32 * wc + 16);
                MFMA_JOB(2, WHH, 128 + 32 * wc);
                MFMA_JOB(3, WHH, 144 + 32 * wc);
                MFMA_JOB(6, WHH, 256 + 32 * wc);
                MFMA_JOB(7, WHH, 272 + 32 * wc);
            }
            #undef MFMA_JOB
        }

        // GRU epilogue (register-local per wave)
        #pragma unroll
        for (int jt = 0; jt < 2; ++jt) {
            int j = 32 * wc + 16 * jt + ln;
            float br  = b_ih[j] + b_hh[j];
            float bz  = b_ih[128 + j] + b_hh[128 + j];
            float bxn = b_ih[256 + j];
            float bhn = b_hh[256 + j];
            #pragma unroll
            for (int mt = 0; mt < 2; ++mt) {
                #pragma unroll
                for (int i = 0; i < 4; ++i) {
                    int row = 32 * wm + mt * 16 + lg * 4 + i;
                    int grow = row0 + row;
                    int lrow = (grow < N) ? grow : (N - 1);
                    float r  = sigmf(acc[mt][jt][i] + br);
                    float z  = sigmf(acc[mt][2 + jt][i] + bz);
                    float xn = acc[mt][4 + jt][i] + bxn;
                    float hn = acc[mt][6 + jt][i] + bhn;
                    float nn = tanh_fast(xn + r * hn);
                    float hp = h[(size_t)lrow * 128 + j];
                    float hv = (1.0f - z) * nn + z * hp;
                    if (grow < N) hnew[(size_t)grow * 128 + j] = hv;
                    int boff = LDS_HO + row * 256 + ((j * 2) ^ ((row & 7) << 4));
                    *reinterpret_cast<unsigned short*>(sm + boff) = f2bf(hv);
                }
            }
        }
    }
    __syncthreads();

    // ---------------- Phase 3: out = h_new @ dec_W.T + dec_b ----------------
    // waves 0..3 handle m-tile w (16 rows); dec_W padded to 16x128 (rows 5..15 zero)
    if (w < 4) {
        f32x4 acc = (f32x4){0.f, 0.f, 0.f, 0.f};
        const unsigned short* DEC = ws + WS_DEC;
        #pragma unroll
        for (int ks = 0; ks < 4; ++ks) {
            int row = w * 16 + ln;
            bf16x8 af = *reinterpret_cast<const bf16x8*>(
                sm + LDS_HO + row * 256 + ((ks * 64 + lg * 16) ^ ((row & 7) << 4)));
            bf16x8 bf = *reinterpret_cast<const bf16x8*>(DEC + (size_t)ln * 128 + ks * 32 + lg * 8);
            acc = __builtin_amdgcn_mfma_f32_16x16x32_bf16(af, bf, acc, 0, 0, 0);
        }
        if (ln < 5) {
            float bias = dec_b[ln];
            #pragma unroll
            for (int i = 0; i < 4; ++i) {
                int grow = row0 + w * 16 + lg * 4 + i;
                if (grow < N) out[(size_t)grow * 5 + ln] = acc[i] + bias;
            }
        }
    }
}

extern "C" void kernel_launch(void* const* d_in, const int* in_sizes, int n_in,
                              void* d_out, int out_size, void* d_ws, size_t ws_size,
                              hipStream_t stream) {
    const float* pos     = (const float*)d_in[0];
    const float* h_other = (const float*)d_in[1];
    const float* h       = (const float*)d_in[2];
    const float* enc_W   = (const float*)d_in[3];
    const float* enc_b   = (const float*)d_in[4];
    const float* henc_W  = (const float*)d_in[5];
    const float* henc_b  = (const float*)d_in[6];
    const float* W_ih    = (const float*)d_in[7];
    const float* b_ih    = (const float*)d_in[8];
    const float* W_hh    = (const float*)d_in[9];
    const float* b_hh    = (const float*)d_in[10];
    const float* dec_W   = (const float*)d_in[11];
    const float* dec_b   = (const float*)d_in[12];

    int N = in_sizes[0] / 2;
    unsigned short* ws = (unsigned short*)d_ws;
    float* out  = (float*)d_out;
    float* hnew = out + (size_t)N * 5;

    hipLaunchKernelGGL(convert_weights_kernel, dim3((WS_TOTAL + 255) / 256), dim3(256), 0, stream,
                       W_ih, W_hh, henc_W, dec_W, ws);
    int blocks = (N + 63) / 64;
    hipLaunchKernelGGL(fused_rnn_kernel, dim3(blocks), dim3(512), 0, stream,
                       pos, h_other, h, enc_W, enc_b, henc_b, b_ih, b_hh, dec_b,
                       ws, out, hnew, N);
}

// Round 4
// 536.761 us; speedup vs baseline: 1.1880x; 1.1880x over previous
//
#include <hip/hip_runtime.h>
#include <hip/hip_bf16.h>
#include <stdint.h>

typedef __bf16 bf16x8 __attribute__((ext_vector_type(8)));
typedef float f32x4 __attribute__((ext_vector_type(4)));

// ---- ws element offsets (ushort) ----
#define C_HENC 0          // [64][256] henc, plain row-major
#define C_GATE 16384      // 8 chunks of [384][32] (t<4: W_ih k=t*32.., t>=4: W_hh)
#define C_DEC  114688     // [16][128] (rows 5..15 zero)
#define WS_TOTAL 116736

// ---- LDS byte offsets ----
#define LDS_X  0          // [64][256B] bf16 swizzled; x=[E1|E2], later h_new
#define LDS_H  16384      // [64][256B] bf16 swizzled
#define LDS_W0 32768      // 24KB gate-chunk buffer 0 ([384][64B], row-XOR swizzled)
#define LDS_W1 57344      // 24KB gate-chunk buffer 1
#define LDS_SZ 81920

__device__ __forceinline__ unsigned short f2bf(float f) {
    unsigned u = __float_as_uint(f);
    unsigned r = (u + 0x7FFFu + ((u >> 16) & 1u)) >> 16;   // RNE
    return (unsigned short)r;
}

__device__ __forceinline__ unsigned cvt_pk_bf16(float a, float b) {
    unsigned r;
    asm("v_cvt_pk_bf16_f32 %0, %1, %2" : "=v"(r) : "v"(a), "v"(b));
    return r;
}

__device__ __forceinline__ float fast_rcp(float x) { return __builtin_amdgcn_rcpf(x); }
__device__ __forceinline__ float sigmf(float x) { return fast_rcp(1.0f + __expf(-x)); }
__device__ __forceinline__ float tanh_fast(float x) {
    float t = __expf(-2.0f * fabsf(x));
    float r = (1.0f - t) * fast_rcp(1.0f + t);
    return copysignf(r, x);
}

// chunk LDS swizzle: linear byte lin -> swizzled byte (2-way-free Bf reads)
__device__ __forceinline__ int chunk_swz(int lin) {
    int brow = lin >> 6;
    return (brow << 6) + ((lin & 63) ^ (((brow >> 1) & 3) << 4));
}

__global__ void convert_weights_kernel(const float* __restrict__ wih,
                                       const float* __restrict__ whh,
                                       const float* __restrict__ henc,
                                       const float* __restrict__ dec,
                                       unsigned short* __restrict__ ws) {
    int i = blockIdx.x * 256 + threadIdx.x;
    if (i >= WS_TOTAL) return;
    float v;
    if (i < C_GATE) {
        v = henc[i];                       // plain [64][256]
    } else if (i < C_DEC) {
        int j = i - C_GATE;
        int t = j / 12288;
        int r2 = j % 12288;
        int row = r2 >> 5;
        int k = r2 & 31;
        v = (t < 4) ? wih[row * 128 + t * 32 + k]
                    : whh[row * 128 + (t - 4) * 32 + k];
    } else {
        int j = i - C_DEC;
        int row = j >> 7, k = j & 127;
        v = (row < 5) ? dec[row * 128 + k] : 0.0f;
    }
    ws[i] = f2bf(v);
}

__launch_bounds__(256, 2)
__global__ void fused_rnn_kernel(const float* __restrict__ pos,
                                 const float* __restrict__ h_other,
                                 const float* __restrict__ h,
                                 const float* __restrict__ enc_W,
                                 const float* __restrict__ enc_b,
                                 const float* __restrict__ henc_b,
                                 const float* __restrict__ b_ih,
                                 const float* __restrict__ b_hh,
                                 const float* __restrict__ dec_b,
                                 const unsigned short* __restrict__ ws,
                                 float* __restrict__ out,
                                 float* __restrict__ hnew,
                                 int N) {
    __shared__ char sm[LDS_SZ];
    const int tid = threadIdx.x;
    const int w   = tid >> 6;      // wave 0..3
    const int l   = tid & 63;
    const int lg  = l >> 4;
    const int ln  = l & 15;
    const int row0 = blockIdx.x * 64;
    const char* wsb = (const char*)ws;

    // ---------------- Phase 0: stage tiles + chunk 0 ----------------
    // chunk 0 loads (issue early, write late)
    uint4 st[6];
    {
        const char* src = wsb + (size_t)C_GATE * 2;
        #pragma unroll
        for (int it = 0; it < 6; ++it)
            st[it] = *reinterpret_cast<const uint4*>(src + it * 4096 + tid * 16);
    }
    // h -> LDS_H (bf16, 64x128, swizzled)
    #pragma unroll
    for (int j = 0; j < 8; ++j) {
        int e0  = (tid + 256 * j) * 4;
        int row = e0 >> 7;
        int col = e0 & 127;
        int grow = row0 + row; if (grow > N - 1) grow = N - 1;
        float4 v = *reinterpret_cast<const float4*>(h + (size_t)grow * 128 + col);
        uint2 p;
        p.x = cvt_pk_bf16(v.x, v.y);
        p.y = cvt_pk_bf16(v.z, v.w);
        int boff = LDS_H + row * 256 + ((col * 2) ^ ((row & 7) << 4));
        *reinterpret_cast<uint2*>(sm + boff) = p;
    }
    // E1 = relu(pos @ enc_W.T + enc_b) -> X cols 0..63
    {
        int row = tid >> 2;
        int c0  = (tid & 3) * 16;
        int grow = row0 + row; if (grow > N - 1) grow = N - 1;
        float p0 = pos[(size_t)grow * 2 + 0];
        float p1 = pos[(size_t)grow * 2 + 1];
        #pragma unroll
        for (int q = 0; q < 8; ++q) {
            int c = c0 + q * 2;
            float v0 = fmaxf(p0 * enc_W[c * 2]     + p1 * enc_W[c * 2 + 1] + enc_b[c], 0.f);
            float v1 = fmaxf(p0 * enc_W[c * 2 + 2] + p1 * enc_W[c * 2 + 3] + enc_b[c + 1], 0.f);
            unsigned pk = cvt_pk_bf16(v0, v1);
            int boff = LDS_X + row * 256 + ((c * 2) ^ ((row & 7) << 4));
            *reinterpret_cast<unsigned*>(sm + boff) = pk;
        }
    }
    // chunk 0 writes -> W0 (swizzled)
    #pragma unroll
    for (int it = 0; it < 6; ++it) {
        int lin = it * 4096 + tid * 16;
        *reinterpret_cast<uint4*>(sm + LDS_W0 + chunk_swz(lin)) = st[it];
    }
    __syncthreads();

    // ---------------- Phase 1: E2 = relu(h_other @ henc_W.T + b) ----------------
    // wave w owns E2 cols [16w,16w+16). B hoisted from ws (L2); A direct from global f32.
    {
        bf16x8 Bh[8];
        const unsigned short* hb = ws + C_HENC + (size_t)(16 * w + ln) * 256;
        #pragma unroll
        for (int ks = 0; ks < 8; ++ks)
            Bh[ks] = *reinterpret_cast<const bf16x8*>(hb + ks * 32 + lg * 8);

        f32x4 e2[4];
        #pragma unroll
        for (int mt = 0; mt < 4; ++mt) e2[mt] = (f32x4){0.f, 0.f, 0.f, 0.f};
        #pragma unroll
        for (int mt = 0; mt < 4; ++mt) {
            int grow = row0 + 16 * mt + ln; if (grow > N - 1) grow = N - 1;
            const float* rp = h_other + (size_t)grow * 256 + lg * 8;
            #pragma unroll
            for (int ks = 0; ks < 8; ++ks) {
                const float* ap = rp + ks * 32;
                float4 a0 = *reinterpret_cast<const float4*>(ap);
                float4 a1 = *reinterpret_cast<const float4*>(ap + 4);
                union { unsigned u[4]; bf16x8 b; } af;
                af.u[0] = cvt_pk_bf16(a0.x, a0.y);
                af.u[1] = cvt_pk_bf16(a0.z, a0.w);
                af.u[2] = cvt_pk_bf16(a1.x, a1.y);
                af.u[3] = cvt_pk_bf16(a1.z, a1.w);
                e2[mt] = __builtin_amdgcn_mfma_f32_16x16x32_bf16(af.b, Bh[ks], e2[mt], 0, 0, 0);
            }
        }
        // E2 epilogue -> X cols 64..127
        int col = 16 * w + ln;
        float bias = henc_b[col];
        #pragma unroll
        for (int mt = 0; mt < 4; ++mt)
            #pragma unroll
            for (int i = 0; i < 4; ++i) {
                int row = 16 * mt + lg * 4 + i;
                float v = fmaxf(e2[mt][i] + bias, 0.f);
                *reinterpret_cast<unsigned short*>(
                    sm + LDS_X + row * 256 + (((64 + col) * 2) ^ ((row & 7) << 4))) = f2bf(v);
            }
    }
    __syncthreads();   // X complete; chunk-0 writes visible

    // ---------------- Phase 2: gates, 8 streamed weight chunks ----------------
    // wave w owns gate cols [32w,32w+32) x all 64 rows.
    f32x4 acc[4][8];
    #pragma unroll
    for (int a = 0; a < 4; ++a)
        #pragma unroll
        for (int b = 0; b < 8; ++b) acc[a][b] = (f32x4){0.f, 0.f, 0.f, 0.f};

    #pragma unroll
    for (int t = 0; t < 8; ++t) {
        const int wb    = (t & 1) ? LDS_W1 : LDS_W0;
        const int wbn   = (t & 1) ? LDS_W0 : LDS_W1;
        const int abase = (t < 4) ? LDS_X : LDS_H;
        const int kb    = (t & 3) * 64;
        // issue next-chunk loads early
        uint4 cs[6];
        if (t < 7) {
            const char* src = wsb + (size_t)(C_GATE + (t + 1) * 12288) * 2;
            #pragma unroll
            for (int it = 0; it < 6; ++it)
                cs[it] = *reinterpret_cast<const uint4*>(src + it * 4096 + tid * 16);
        }
        // B-frags (6) from swizzled chunk buffer
        bf16x8 Bf[6];
        #pragma unroll
        for (int g = 0; g < 3; ++g)
            #pragma unroll
            for (int jt = 0; jt < 2; ++jt) {
                int brow = g * 128 + 32 * w + 16 * jt + ln;
                Bf[g * 2 + jt] = *reinterpret_cast<const bf16x8*>(
                    sm + wb + brow * 64 + (lg * 16 ^ (((brow >> 1) & 3) << 4)));
            }
        // A-frags (4)
        bf16x8 Af[4];
        const int swl = (ln & 7) << 4;
        #pragma unroll
        for (int mt = 0; mt < 4; ++mt) {
            int row = 16 * mt + ln;
            Af[mt] = *reinterpret_cast<const bf16x8*>(
                sm + abase + row * 256 + ((kb + lg * 16) ^ swl));
        }
        // MFMAs (24)
        const int nidx = (t < 4) ? 4 : 6;
        #pragma unroll
        for (int mt = 0; mt < 4; ++mt) {
            acc[mt][0]        = __builtin_amdgcn_mfma_f32_16x16x32_bf16(Af[mt], Bf[0], acc[mt][0], 0, 0, 0);
            acc[mt][1]        = __builtin_amdgcn_mfma_f32_16x16x32_bf16(Af[mt], Bf[1], acc[mt][1], 0, 0, 0);
            acc[mt][2]        = __builtin_amdgcn_mfma_f32_16x16x32_bf16(Af[mt], Bf[2], acc[mt][2], 0, 0, 0);
            acc[mt][3]        = __builtin_amdgcn_mfma_f32_16x16x32_bf16(Af[mt], Bf[3], acc[mt][3], 0, 0, 0);
            acc[mt][nidx]     = __builtin_amdgcn_mfma_f32_16x16x32_bf16(Af[mt], Bf[4], acc[mt][nidx], 0, 0, 0);
            acc[mt][nidx + 1] = __builtin_amdgcn_mfma_f32_16x16x32_bf16(Af[mt], Bf[5], acc[mt][nidx + 1], 0, 0, 0);
        }
        // write staged chunk -> wbn (swizzled); safe: wbn reads drained at t-1 barrier
        if (t < 7) {
            #pragma unroll
            for (int it = 0; it < 6; ++it) {
                int lin = it * 4096 + tid * 16;
                *reinterpret_cast<uint4*>(sm + wbn + chunk_swz(lin)) = cs[it];
            }
        }
        __syncthreads();
    }

    // ---------------- GRU epilogue (register-local; h from global f32) ----------------
    #pragma unroll
    for (int jt = 0; jt < 2; ++jt) {
        int j = 32 * w + 16 * jt + ln;
        float br  = b_ih[j] + b_hh[j];
        float bz  = b_ih[128 + j] + b_hh[128 + j];
        float bxn = b_ih[256 + j];
        float bhn = b_hh[256 + j];
        #pragma unroll
        for (int mt = 0; mt < 4; ++mt)
            #pragma unroll
            for (int i = 0; i < 4; ++i) {
                int row = mt * 16 + lg * 4 + i;
                int grow = row0 + row;
                int lrow = (grow < N) ? grow : (N - 1);
                float r  = sigmf(acc[mt][jt][i] + br);
                float z  = sigmf(acc[mt][2 + jt][i] + bz);
                float xn = acc[mt][4 + jt][i] + bxn;
                float hn = acc[mt][6 + jt][i] + bhn;
                float nn = tanh_fast(xn + r * hn);
                float hp = h[(size_t)lrow * 128 + j];
                float hv = (1.0f - z) * nn + z * hp;
                if (grow < N) hnew[(size_t)grow * 128 + j] = hv;
                *reinterpret_cast<unsigned short*>(
                    sm + LDS_X + row * 256 + ((j * 2) ^ ((row & 7) << 4))) = f2bf(hv);
            }
    }
    __syncthreads();

    // ---------------- Phase 3: out = h_new @ dec_W.T + dec_b ----------------
    {
        f32x4 oc = (f32x4){0.f, 0.f, 0.f, 0.f};
        #pragma unroll
        for (int ks = 0; ks < 4; ++ks) {
            int row = 16 * w + ln;
            bf16x8 af = *reinterpret_cast<const bf16x8*>(
                sm + LDS_X + row * 256 + ((ks * 64 + lg * 16) ^ ((row & 7) << 4)));
            bf16x8 bf = *reinterpret_cast<const bf16x8*>(ws + C_DEC + ln * 128 + ks * 32 + lg * 8);
            oc = __builtin_amdgcn_mfma_f32_16x16x32_bf16(af, bf, oc, 0, 0, 0);
        }
        if (ln < 5) {
            float bias = dec_b[ln];
            #pragma unroll
            for (int i = 0; i < 4; ++i) {
                int grow = row0 + 16 * w + lg * 4 + i;
                if (grow < N) out[(size_t)grow * 5 + ln] = oc[i] + bias;
            }
        }
    }
}

extern "C" void kernel_launch(void* const* d_in, const int* in_sizes, int n_in,
                              void* d_out, int out_size, void* d_ws, size_t ws_size,
                              hipStream_t stream) {
    const float* pos     = (const float*)d_in[0];
    const float* h_other = (const float*)d_in[1];
    const float* h       = (const float*)d_in[2];
    const float* enc_W   = (const float*)d_in[3];
    const float* enc_b   = (const float*)d_in[4];
    const float* henc_W  = (const float*)d_in[5];
    const float* henc_b  = (const float*)d_in[6];
    const float* W_ih    = (const float*)d_in[7];
    const float* b_ih    = (const float*)d_in[8];
    const float* W_hh    = (const float*)d_in[9];
    const float* b_hh    = (const float*)d_in[10];
    const float* dec_W   = (const float*)d_in[11];
    const float* dec_b   = (const float*)d_in[12];

    int N = in_sizes[0] / 2;
    unsigned short* ws = (unsigned short*)d_ws;
    float* out  = (float*)d_out;
    float* hnew = out + (size_t)N * 5;

    hipLaunchKernelGGL(convert_weights_kernel, dim3((WS_TOTAL + 255) / 256), dim3(256), 0, stream,
                       W_ih, W_hh, henc_W, dec_W, ws);
    int blocks = (N + 63) / 64;
    hipLaunchKernelGGL(fused_rnn_kernel, dim3(blocks), dim3(256), 0, stream,
                       pos, h_other, h, enc_W, enc_b, henc_b, b_ih, b_hh, dec_b,
                       ws, out, hnew, N);
}